// Round 1
// baseline (676.321 us; speedup 1.0000x reference)
//
#include <hip/hip_runtime.h>
#include <stdint.h>

#define NA 250000
#define NC 80
#define KSEL 2048
#define CONF_THF 0.05f
#define IOU_THF 0.5f

typedef unsigned int u32;
typedef unsigned long long u64;

// ---- workspace layout (bytes) ----
#define WS_HIST1   0u          // 65536 u32 (256KB)
#define WS_HIST2   262144u     // 65536 u32 (256KB)
#define WS_SCAL    524288u     // 16 u32: 0=binB 1=countAbove 2=kthKey 3=candCnt 4=maxCoordBits
#define WS_MAXS    524352u     // 250000 f32
#define WS_LABELS  1524352u    // 250000 i32
#define WS_CAND    2524352u    // 8192 u32
#define WS_SIDX    2557120u    // 2048 u32
#define WS_VALID   2565312u    // 2048 u32
#define WS_MASK    2573504u    // 2048*32 u64 (512KB), 8B aligned

// Correctly-rounded f32 sigmoid: f32 exp via double, then exact f32 arithmetic
// (matches 1/(1+exp(-x)) with a correctly-rounded exp — best shot at matching
// the numpy reference's float32 values bit-for-bit for order-critical anchors).
__device__ __forceinline__ float sigmoidf_(float x) {
  if (x >= 0.0f) {
    float ef = (float)exp(-(double)x);
    return 1.0f / (1.0f + ef);
  } else {
    float ef = (float)exp((double)x);
    return ef / (1.0f + ef);
  }
}

__device__ __forceinline__ u64 bcast64(u64 v, int src) {
  u32 lo = (u32)v, hi = (u32)(v >> 32);
  lo = __shfl((int)lo, src);
  hi = __shfl((int)hi, src);
  return ((u64)hi << 32) | (u64)lo;
}

// K1: fused scores + max/argmax + histogram of high-16 key bits.
__global__ void k1_scores(const float* __restrict__ cls, const float* __restrict__ cent,
                          float* __restrict__ maxs, int* __restrict__ labels,
                          u32* __restrict__ hist1) {
  int t = blockIdx.x * blockDim.x + threadIdx.x;
  int a = t >> 2, p = t & 3;
  if (a >= NA) return;
  float cp = sigmoidf_(cent[a]);
  const float4* row = (const float4*)(cls + (size_t)a * NC + (size_t)p * 20);
  float bs = -1.0f; int bc = 0;
#pragma unroll
  for (int i = 0; i < 5; i++) {
    float4 v = row[i];
    float ss[4] = {v.x, v.y, v.z, v.w};
#pragma unroll
    for (int q = 0; q < 4; q++) {
      float s = sigmoidf_(ss[q]) * cp;
      int c = p * 20 + i * 4 + q;
      if (s > bs) { bs = s; bc = c; }   // strict > => first-index argmax
    }
  }
#pragma unroll
  for (int off = 1; off <= 2; off <<= 1) {
    float os = __shfl_xor(bs, off);
    int   oc = __shfl_xor(bc, off);
    if (os > bs || (os == bs && oc < bc)) { bs = os; bc = oc; }
  }
  if (p == 0) {
    maxs[a] = bs;
    labels[a] = bc;
    u32 key = (bs > CONF_THF) ? __float_as_uint(bs) : 0u;
    atomicAdd(&hist1[key >> 16], 1u);
  }
}

// K2: find the high-16 bin containing rank KSEL (from the top).
__global__ void __launch_bounds__(1024) k2_findbin(const u32* __restrict__ hist1,
                                                   u32* __restrict__ scal) {
  __shared__ u32 part[1024];
  int tid = threadIdx.x;
  u32 s = 0;
  for (int i = 0; i < 64; i++) s += hist1[tid * 64 + i];
  part[tid] = s;
  __syncthreads();
  if (tid == 0) {
    u32 above = 0; int chunk = 0;
    for (int t2 = 1023; t2 >= 0; t2--) {
      if (above + part[t2] >= KSEL) { chunk = t2; break; }
      above += part[t2];
    }
    int binB = chunk * 64;
    for (int b = chunk * 64 + 63; b >= chunk * 64; b--) {
      if (above + hist1[b] >= KSEL) { binB = b; break; }
      above += hist1[b];
    }
    scal[0] = (u32)binB;
    scal[1] = above;   // strictly above binB
  }
}

// K3: low-16 histogram within bin B.
__global__ void k3_hist2(const float* __restrict__ maxs, const u32* __restrict__ scal,
                         u32* __restrict__ hist2) {
  int a = blockIdx.x * blockDim.x + threadIdx.x;
  if (a >= NA) return;
  float s = maxs[a];
  u32 key = (s > CONF_THF) ? __float_as_uint(s) : 0u;
  if ((key >> 16) == scal[0]) atomicAdd(&hist2[key & 0xFFFFu], 1u);
}

// K4: find exact kth key.
__global__ void __launch_bounds__(1024) k4_findlow(const u32* __restrict__ hist2,
                                                   u32* __restrict__ scal) {
  __shared__ u32 part[1024];
  int tid = threadIdx.x;
  u32 s = 0;
  for (int i = 0; i < 64; i++) s += hist2[tid * 64 + i];
  part[tid] = s;
  __syncthreads();
  if (tid == 0) {
    u32 above = scal[1];
    int chunk = 0;
    for (int t2 = 1023; t2 >= 0; t2--) {
      if (above + part[t2] >= KSEL) { chunk = t2; break; }
      above += part[t2];
    }
    u32 kth = scal[0] << 16;
    for (int l = chunk * 64 + 63; l >= chunk * 64; l--) {
      if (above + hist2[l] >= KSEL) { kth |= (u32)l; break; }
      above += hist2[l];
    }
    scal[2] = kth;
  }
}

// K5: compact candidates with key >= kth.
__global__ void k5_compact(const float* __restrict__ maxs, u32* __restrict__ scal,
                           u32* __restrict__ cand) {
  int a = blockIdx.x * blockDim.x + threadIdx.x;
  if (a >= NA) return;
  float s = maxs[a];
  u32 key = (s > CONF_THF) ? __float_as_uint(s) : 0u;
  u32 kth = scal[2];
  // kth==0 fallback: only zero-keys with idx<KSEL are needed (smallest indices win ties)
  if (key >= kth && (key > 0u || a < KSEL)) {
    u32 pos = atomicAdd(&scal[3], 1u);
    if (pos < 8192u) cand[pos] = (u32)a;
  }
}

// K6: bitonic sort 4096 candidates by (score_bits desc, idx asc); emit top 2048.
__global__ void __launch_bounds__(1024) k6_sort(const float* __restrict__ maxs,
                                                const u32* __restrict__ cand,
                                                const u32* __restrict__ scal,
                                                u32* __restrict__ sidx,
                                                u32* __restrict__ validArr) {
  __shared__ u64 skey[4096];
  int tid = threadIdx.x;
  u32 cnt = scal[3];
  u32 n = cnt < 4096u ? cnt : 4096u;
  for (int i = tid; i < 4096; i += 1024) {
    u64 key = 0;
    if ((u32)i < n) {
      u32 a = cand[i];
      float s = maxs[a];
      u32 kb = (s > CONF_THF) ? __float_as_uint(s) : 0u;
      key = ((u64)kb << 32) | (u64)(0xFFFFFFFFu - a);
    }
    skey[i] = key;
  }
  for (int k = 2; k <= 4096; k <<= 1) {
    for (int j = k >> 1; j > 0; j >>= 1) {
      __syncthreads();
      for (int i = tid; i < 4096; i += 1024) {
        int l = i ^ j;
        if (l > i) {
          u64 A = skey[i], B = skey[l];
          bool desc = ((i & k) == 0);
          if (desc ? (A < B) : (A > B)) { skey[i] = B; skey[l] = A; }
        }
      }
    }
  }
  __syncthreads();
  for (int r = tid; r < KSEL; r += 1024) {
    u64 kk = skey[r];
    u32 a = 0xFFFFFFFFu - (u32)(kk & 0xFFFFFFFFu);
    sidx[r] = a;
    validArr[r] = ((kk >> 32) != 0ull) ? 1u : 0u;
  }
}

// K7: gather outputs + max_coord reduction.
__global__ void k7_gather(const float* __restrict__ cls, const float* __restrict__ cent,
                          const float* __restrict__ bbox, const float* __restrict__ maxs,
                          const int* __restrict__ labels, const u32* __restrict__ sidx,
                          const u32* __restrict__ validArr, u32* __restrict__ scal,
                          float* __restrict__ out) {
  int r = blockIdx.x;
  int tid = threadIdx.x;
  u32 a = sidx[r];
  float* out_boxes  = out;
  float* out_scores = out + KSEL * 4;
  float* out_ms     = out + KSEL * 4 + KSEL * NC;
  float* out_lab    = out_ms + KSEL;
  if (tid < NC) {
    float cp = sigmoidf_(cent[a]);
    float s = sigmoidf_(cls[(size_t)a * NC + tid]) * cp;
    out_scores[(size_t)r * NC + tid] = s;
  } else if (tid < NC + 4) {
    int q = tid - NC;
    float v = bbox[(size_t)a * 4 + q];
    out_boxes[r * 4 + q] = v;
    if (validArr[r]) atomicMax((int*)&scal[4], __float_as_int(v));  // coords >= 0
  } else if (tid == NC + 4) {
    out_ms[r] = maxs[a];
  } else if (tid == NC + 5) {
    out_lab[r] = (float)labels[a];
  }
}

// K8: 64x64 IoU tiles -> suppression bitmask.
__global__ void k8_mask(const float* __restrict__ out, const u32* __restrict__ scal,
                        u64* __restrict__ mask) {
  __shared__ float cx1[64], cy1[64], cx2[64], cy2[64], car[64];
  const float* boxes = out;
  const float* lab = out + KSEL * 4 + KSEL * NC + KSEL;
  float mc1 = __int_as_float(*(const int*)&scal[4]) + 1.0f;
  int t = threadIdx.x;
  int j = blockIdx.x * 64 + t;
  {
    float off = lab[j] * mc1;
    float x1 = boxes[j * 4 + 0] + off, y1 = boxes[j * 4 + 1] + off;
    float x2 = boxes[j * 4 + 2] + off, y2 = boxes[j * 4 + 3] + off;
    cx1[t] = x1; cy1[t] = y1; cx2[t] = x2; cy2[t] = y2;
    car[t] = (x2 - x1) * (y2 - y1);
  }
  __syncthreads();
  int i = blockIdx.y * 64 + t;
  float off = lab[i] * mc1;
  float x1 = boxes[i * 4 + 0] + off, y1 = boxes[i * 4 + 1] + off;
  float x2 = boxes[i * 4 + 2] + off, y2 = boxes[i * 4 + 3] + off;
  float ar = (x2 - x1) * (y2 - y1);
  u64 bits = 0;
  for (int jj = 0; jj < 64; jj++) {
    float ix = fminf(x2, cx2[jj]) - fmaxf(x1, cx1[jj]);
    float iy = fminf(y2, cy2[jj]) - fmaxf(y1, cy1[jj]);
    float inter = fmaxf(ix, 0.0f) * fmaxf(iy, 0.0f);
    float uni = ar + car[jj] - inter;
    float iou = inter / fmaxf(uni, 1e-9f);
    if (iou > IOU_THF) bits |= (1ull << jj);
  }
  mask[(size_t)i * 32 + blockIdx.x] = bits;
}

// K9: single-wave sequential greedy NMS with 16-row register prefetch.
__global__ void k9_nms(const u64* __restrict__ mask, const u32* __restrict__ validArr,
                       float* __restrict__ out_keep) {
  int lane = threadIdx.x;
  u64 vw = 0, remv = 0;
  if (lane < 32) {
    const u32* va = validArr + lane * 64;
#pragma unroll 8
    for (int b = 0; b < 64; b++) vw |= ((u64)(va[b] & 1u)) << b;
  }
  u64 cur[16], nxt[16];
  if (lane < 32) {
#pragma unroll
    for (int k = 0; k < 16; k++) cur[k] = mask[(size_t)k * 32 + lane];
  }
  for (int g = 0; g < KSEL; g += 16) {
    if (g + 16 < KSEL && lane < 32) {
#pragma unroll
      for (int k = 0; k < 16; k++) nxt[k] = mask[(size_t)(g + 16 + k) * 32 + lane];
    }
#pragma unroll
    for (int k = 0; k < 16; k++) {
      int i = g + k;
      int wi = i >> 6, bi = i & 63;
      u64 rw = bcast64(remv, wi);
      u64 vv = bcast64(vw, wi);
      bool alive = (((vv >> bi) & 1ull) != 0ull) && (((rw >> bi) & 1ull) == 0ull);
      remv |= alive ? cur[k] : 0ull;
      if (lane == 0) out_keep[i] = alive ? 1.0f : 0.0f;
    }
#pragma unroll
    for (int k = 0; k < 16; k++) cur[k] = nxt[k];
  }
}

extern "C" void kernel_launch(void* const* d_in, const int* in_sizes, int n_in,
                              void* d_out, int out_size, void* d_ws, size_t ws_size,
                              hipStream_t stream) {
  const float* cls  = (const float*)d_in[0];
  const float* bbox = (const float*)d_in[1];
  const float* cent = (const float*)d_in[2];
  float* out = (float*)d_out;
  char* ws = (char*)d_ws;
  u32* hist1    = (u32*)(ws + WS_HIST1);
  u32* hist2    = (u32*)(ws + WS_HIST2);
  u32* scal     = (u32*)(ws + WS_SCAL);
  float* maxs   = (float*)(ws + WS_MAXS);
  int* labels   = (int*)(ws + WS_LABELS);
  u32* cand     = (u32*)(ws + WS_CAND);
  u32* sidx     = (u32*)(ws + WS_SIDX);
  u32* validArr = (u32*)(ws + WS_VALID);
  u64* mask     = (u64*)(ws + WS_MASK);

  (void)in_sizes; (void)n_in; (void)out_size; (void)ws_size;

  // zero hist1+hist2+scalars each call (deterministic across graph replays)
  hipMemsetAsync(ws, 0, WS_MAXS, stream);

  k1_scores<<<(NA * 4 + 255) / 256, 256, 0, stream>>>(cls, cent, maxs, labels, hist1);
  k2_findbin<<<1, 1024, 0, stream>>>(hist1, scal);
  k3_hist2<<<(NA + 255) / 256, 256, 0, stream>>>(maxs, scal, hist2);
  k4_findlow<<<1, 1024, 0, stream>>>(hist2, scal);
  k5_compact<<<(NA + 255) / 256, 256, 0, stream>>>(maxs, scal, cand);
  k6_sort<<<1, 1024, 0, stream>>>(maxs, cand, scal, sidx, validArr);
  k7_gather<<<KSEL, 128, 0, stream>>>(cls, cent, bbox, maxs, labels, sidx, validArr, scal, out);
  k8_mask<<<dim3(32, 32), 64, 0, stream>>>(out, scal, mask);
  k9_nms<<<1, 64, 0, stream>>>(mask, validArr, out + KSEL * 4 + KSEL * NC + KSEL * 2);
}

// Round 2
// 670.923 us; speedup vs baseline: 1.0080x; 1.0080x over previous
//
#include <hip/hip_runtime.h>
#include <stdint.h>

#define NA 250000
#define NC 80
#define KSEL 2048
#define CONF_THF 0.05f
#define IOU_THF 0.5f

typedef unsigned int u32;
typedef unsigned long long u64;

// ---- workspace layout (bytes) ----
#define WS_HIST1   0u          // 65536 u32 (256KB)
#define WS_HIST2   262144u     // 65536 u32 (256KB)
#define WS_SCAL    524288u     // 16 u32: 0=binB 1=countAbove 2=kthKey 3=candCnt 4=maxCoordBits
#define WS_MAXS    524352u     // 250000 f32
#define WS_LABELS  1524352u    // 250000 i32
#define WS_CAND    2524352u    // 8192 u32
#define WS_SIDX    2557120u    // 2048 u32
#define WS_VALID   2565312u    // 2048 u32
#define WS_MASK    2573504u    // 2048*32 u64 (512KB), 8B aligned

// Correctly-rounded f32 sigmoid via double exp — used ONLY for order-critical
// values (max_scores). Must stay bit-identical to round-1 (known to match the
// numpy reference's ranking on this input).
__device__ __forceinline__ float sigmoidf_(float x) {
  if (x >= 0.0f) {
    float ef = (float)exp(-(double)x);
    return 1.0f / (1.0f + ef);
  } else {
    float ef = (float)exp((double)x);
    return ef / (1.0f + ef);
  }
}

// Fast f32 sigmoid for value-only outputs (scores matrix; tolerance ~0.02).
__device__ __forceinline__ float sigmoid_fast(float x) {
  return 1.0f / (1.0f + __expf(-x));
}

__device__ __forceinline__ u64 bcast64(u64 v, int src) {
  u32 lo = (u32)v, hi = (u32)(v >> 32);
  lo = __shfl((int)lo, src);
  hi = __shfl((int)hi, src);
  return ((u64)hi << 32) | (u64)lo;
}

// K1: max/argmax over classes via RAW LOGITS (sigmoid is monotone); exact
// double-exp sigmoid only for classes within 2e-4 of the max logit (the
// window where f32-rounded products could tie/reorder). ~2 double-sigmoids
// per anchor instead of 21.
__global__ void k1_scores(const float* __restrict__ cls, const float* __restrict__ cent,
                          float* __restrict__ maxs, int* __restrict__ labels,
                          u32* __restrict__ hist1) {
  int t = blockIdx.x * blockDim.x + threadIdx.x;
  int a = t >> 2, p = t & 3;
  if (a >= NA) return;
  const float4* row = (const float4*)(cls + (size_t)a * NC + (size_t)p * 20);
  float v[20];
#pragma unroll
  for (int i = 0; i < 5; i++) {
    float4 w = row[i];
    v[i * 4 + 0] = w.x; v[i * 4 + 1] = w.y; v[i * 4 + 2] = w.z; v[i * 4 + 3] = w.w;
  }
  float lm = -1e30f;
#pragma unroll
  for (int q = 0; q < 20; q++) lm = fmaxf(lm, v[q]);
  lm = fmaxf(lm, __shfl_xor(lm, 1));
  lm = fmaxf(lm, __shfl_xor(lm, 2));   // lm = max logit over 80 classes

  // centerness sigmoid once per anchor (lane p==0), broadcast within quad
  float cp = 0.0f;
  if (p == 0) cp = sigmoidf_(cent[a]);
  int lane = threadIdx.x & 63;
  cp = __shfl(cp, lane & ~3);

  // exact f32 products for near-max classes only
  float thresh = lm - 2e-4f;
  float bs = -1.0f; int bc = 0x7fffffff;
#pragma unroll
  for (int q = 0; q < 20; q++) {
    if (v[q] >= thresh) {
      float s = sigmoidf_(v[q]) * cp;
      int c = p * 20 + q;
      if (s > bs || (s == bs && c < bc)) { bs = s; bc = c; }
    }
  }
#pragma unroll
  for (int off = 1; off <= 2; off <<= 1) {
    float os = __shfl_xor(bs, off);
    int   oc = __shfl_xor(bc, off);
    if (os > bs || (os == bs && oc < bc)) { bs = os; bc = oc; }
  }
  if (p == 0) {
    maxs[a] = bs;
    labels[a] = bc;
    u32 key = (bs > CONF_THF) ? __float_as_uint(bs) : 0u;
    atomicAdd(&hist1[key >> 16], 1u);
  }
}

// K2: find the high-16 bin containing rank KSEL (from the top).
__global__ void __launch_bounds__(1024) k2_findbin(const u32* __restrict__ hist1,
                                                   u32* __restrict__ scal) {
  __shared__ u32 part[1024];
  int tid = threadIdx.x;
  u32 s = 0;
  for (int i = 0; i < 64; i++) s += hist1[tid * 64 + i];
  part[tid] = s;
  __syncthreads();
  if (tid == 0) {
    u32 above = 0; int chunk = 0;
    for (int t2 = 1023; t2 >= 0; t2--) {
      if (above + part[t2] >= KSEL) { chunk = t2; break; }
      above += part[t2];
    }
    int binB = chunk * 64;
    for (int b = chunk * 64 + 63; b >= chunk * 64; b--) {
      if (above + hist1[b] >= KSEL) { binB = b; break; }
      above += hist1[b];
    }
    scal[0] = (u32)binB;
    scal[1] = above;   // strictly above binB
  }
}

// K3: low-16 histogram within bin B.
__global__ void k3_hist2(const float* __restrict__ maxs, const u32* __restrict__ scal,
                         u32* __restrict__ hist2) {
  int a = blockIdx.x * blockDim.x + threadIdx.x;
  if (a >= NA) return;
  float s = maxs[a];
  u32 key = (s > CONF_THF) ? __float_as_uint(s) : 0u;
  if ((key >> 16) == scal[0]) atomicAdd(&hist2[key & 0xFFFFu], 1u);
}

// K4: find exact kth key.
__global__ void __launch_bounds__(1024) k4_findlow(const u32* __restrict__ hist2,
                                                   u32* __restrict__ scal) {
  __shared__ u32 part[1024];
  int tid = threadIdx.x;
  u32 s = 0;
  for (int i = 0; i < 64; i++) s += hist2[tid * 64 + i];
  part[tid] = s;
  __syncthreads();
  if (tid == 0) {
    u32 above = scal[1];
    int chunk = 0;
    for (int t2 = 1023; t2 >= 0; t2--) {
      if (above + part[t2] >= KSEL) { chunk = t2; break; }
      above += part[t2];
    }
    u32 kth = scal[0] << 16;
    for (int l = chunk * 64 + 63; l >= chunk * 64; l--) {
      if (above + hist2[l] >= KSEL) { kth |= (u32)l; break; }
      above += hist2[l];
    }
    scal[2] = kth;
  }
}

// K5: compact candidates with key >= kth.
__global__ void k5_compact(const float* __restrict__ maxs, u32* __restrict__ scal,
                           u32* __restrict__ cand) {
  int a = blockIdx.x * blockDim.x + threadIdx.x;
  if (a >= NA) return;
  float s = maxs[a];
  u32 key = (s > CONF_THF) ? __float_as_uint(s) : 0u;
  u32 kth = scal[2];
  // kth==0 fallback: only zero-keys with idx<KSEL are needed (smallest indices win ties)
  if (key >= kth && (key > 0u || a < KSEL)) {
    u32 pos = atomicAdd(&scal[3], 1u);
    if (pos < 8192u) cand[pos] = (u32)a;
  }
}

// K6: bitonic sort 4096 candidates by (score_bits desc, idx asc); emit top 2048.
__global__ void __launch_bounds__(1024) k6_sort(const float* __restrict__ maxs,
                                                const u32* __restrict__ cand,
                                                const u32* __restrict__ scal,
                                                u32* __restrict__ sidx,
                                                u32* __restrict__ validArr) {
  __shared__ u64 skey[4096];
  int tid = threadIdx.x;
  u32 cnt = scal[3];
  u32 n = cnt < 4096u ? cnt : 4096u;
  for (int i = tid; i < 4096; i += 1024) {
    u64 key = 0;
    if ((u32)i < n) {
      u32 a = cand[i];
      float s = maxs[a];
      u32 kb = (s > CONF_THF) ? __float_as_uint(s) : 0u;
      key = ((u64)kb << 32) | (u64)(0xFFFFFFFFu - a);
    }
    skey[i] = key;
  }
  for (int k = 2; k <= 4096; k <<= 1) {
    for (int j = k >> 1; j > 0; j >>= 1) {
      __syncthreads();
      for (int i = tid; i < 4096; i += 1024) {
        int l = i ^ j;
        if (l > i) {
          u64 A = skey[i], B = skey[l];
          bool desc = ((i & k) == 0);
          if (desc ? (A < B) : (A > B)) { skey[i] = B; skey[l] = A; }
        }
      }
    }
  }
  __syncthreads();
  for (int r = tid; r < KSEL; r += 1024) {
    u64 kk = skey[r];
    u32 a = 0xFFFFFFFFu - (u32)(kk & 0xFFFFFFFFu);
    sidx[r] = a;
    validArr[r] = ((kk >> 32) != 0ull) ? 1u : 0u;
  }
}

// K7: gather outputs + max_coord reduction. Scores output uses fast sigmoid
// (value-only, tolerance ~0.02); ordering-critical values come from maxs.
__global__ void k7_gather(const float* __restrict__ cls, const float* __restrict__ cent,
                          const float* __restrict__ bbox, const float* __restrict__ maxs,
                          const int* __restrict__ labels, const u32* __restrict__ sidx,
                          const u32* __restrict__ validArr, u32* __restrict__ scal,
                          float* __restrict__ out) {
  int r = blockIdx.x;
  int tid = threadIdx.x;
  u32 a = sidx[r];
  float* out_boxes  = out;
  float* out_scores = out + KSEL * 4;
  float* out_ms     = out + KSEL * 4 + KSEL * NC;
  float* out_lab    = out_ms + KSEL;
  if (tid < NC) {
    float cp = sigmoid_fast(cent[a]);
    float s = sigmoid_fast(cls[(size_t)a * NC + tid]) * cp;
    out_scores[(size_t)r * NC + tid] = s;
  } else if (tid < NC + 4) {
    int q = tid - NC;
    float v = bbox[(size_t)a * 4 + q];
    out_boxes[r * 4 + q] = v;
    if (validArr[r]) atomicMax((int*)&scal[4], __float_as_int(v));  // coords >= 0
  } else if (tid == NC + 4) {
    out_ms[r] = maxs[a];
  } else if (tid == NC + 5) {
    out_lab[r] = (float)labels[a];
  }
}

// K8: 64x64 IoU tiles -> suppression bitmask.
__global__ void k8_mask(const float* __restrict__ out, const u32* __restrict__ scal,
                        u64* __restrict__ mask) {
  __shared__ float cx1[64], cy1[64], cx2[64], cy2[64], car[64];
  const float* boxes = out;
  const float* lab = out + KSEL * 4 + KSEL * NC + KSEL;
  float mc1 = __int_as_float(*(const int*)&scal[4]) + 1.0f;
  int t = threadIdx.x;
  int j = blockIdx.x * 64 + t;
  {
    float off = lab[j] * mc1;
    float x1 = boxes[j * 4 + 0] + off, y1 = boxes[j * 4 + 1] + off;
    float x2 = boxes[j * 4 + 2] + off, y2 = boxes[j * 4 + 3] + off;
    cx1[t] = x1; cy1[t] = y1; cx2[t] = x2; cy2[t] = y2;
    car[t] = (x2 - x1) * (y2 - y1);
  }
  __syncthreads();
  int i = blockIdx.y * 64 + t;
  float off = lab[i] * mc1;
  float x1 = boxes[i * 4 + 0] + off, y1 = boxes[i * 4 + 1] + off;
  float x2 = boxes[i * 4 + 2] + off, y2 = boxes[i * 4 + 3] + off;
  float ar = (x2 - x1) * (y2 - y1);
  u64 bits = 0;
  for (int jj = 0; jj < 64; jj++) {
    float ix = fminf(x2, cx2[jj]) - fmaxf(x1, cx1[jj]);
    float iy = fminf(y2, cy2[jj]) - fmaxf(y1, cy1[jj]);
    float inter = fmaxf(ix, 0.0f) * fmaxf(iy, 0.0f);
    float uni = ar + car[jj] - inter;
    float iou = inter / fmaxf(uni, 1e-9f);
    if (iou > IOU_THF) bits |= (1ull << jj);
  }
  mask[(size_t)i * 32 + blockIdx.x] = bits;
}

// K9: single-wave sequential greedy NMS with 16-row register prefetch.
__global__ void k9_nms(const u64* __restrict__ mask, const u32* __restrict__ validArr,
                       float* __restrict__ out_keep) {
  int lane = threadIdx.x;
  u64 vw = 0, remv = 0;
  if (lane < 32) {
    const u32* va = validArr + lane * 64;
#pragma unroll 8
    for (int b = 0; b < 64; b++) vw |= ((u64)(va[b] & 1u)) << b;
  }
  u64 cur[16], nxt[16];
  if (lane < 32) {
#pragma unroll
    for (int k = 0; k < 16; k++) cur[k] = mask[(size_t)k * 32 + lane];
  }
  for (int g = 0; g < KSEL; g += 16) {
    if (g + 16 < KSEL && lane < 32) {
#pragma unroll
      for (int k = 0; k < 16; k++) nxt[k] = mask[(size_t)(g + 16 + k) * 32 + lane];
    }
#pragma unroll
    for (int k = 0; k < 16; k++) {
      int i = g + k;
      int wi = i >> 6, bi = i & 63;
      u64 rw = bcast64(remv, wi);
      u64 vv = bcast64(vw, wi);
      bool alive = (((vv >> bi) & 1ull) != 0ull) && (((rw >> bi) & 1ull) == 0ull);
      remv |= alive ? cur[k] : 0ull;
      if (lane == 0) out_keep[i] = alive ? 1.0f : 0.0f;
    }
#pragma unroll
    for (int k = 0; k < 16; k++) cur[k] = nxt[k];
  }
}

extern "C" void kernel_launch(void* const* d_in, const int* in_sizes, int n_in,
                              void* d_out, int out_size, void* d_ws, size_t ws_size,
                              hipStream_t stream) {
  const float* cls  = (const float*)d_in[0];
  const float* bbox = (const float*)d_in[1];
  const float* cent = (const float*)d_in[2];
  float* out = (float*)d_out;
  char* ws = (char*)d_ws;
  u32* hist1    = (u32*)(ws + WS_HIST1);
  u32* hist2    = (u32*)(ws + WS_HIST2);
  u32* scal     = (u32*)(ws + WS_SCAL);
  float* maxs   = (float*)(ws + WS_MAXS);
  int* labels   = (int*)(ws + WS_LABELS);
  u32* cand     = (u32*)(ws + WS_CAND);
  u32* sidx     = (u32*)(ws + WS_SIDX);
  u32* validArr = (u32*)(ws + WS_VALID);
  u64* mask     = (u64*)(ws + WS_MASK);

  (void)in_sizes; (void)n_in; (void)out_size; (void)ws_size;

  // zero hist1+hist2+scalars each call (deterministic across graph replays)
  hipMemsetAsync(ws, 0, WS_MAXS, stream);

  k1_scores<<<(NA * 4 + 255) / 256, 256, 0, stream>>>(cls, cent, maxs, labels, hist1);
  k2_findbin<<<1, 1024, 0, stream>>>(hist1, scal);
  k3_hist2<<<(NA + 255) / 256, 256, 0, stream>>>(maxs, scal, hist2);
  k4_findlow<<<1, 1024, 0, stream>>>(hist2, scal);
  k5_compact<<<(NA + 255) / 256, 256, 0, stream>>>(maxs, scal, cand);
  k6_sort<<<1, 1024, 0, stream>>>(maxs, cand, scal, sidx, validArr);
  k7_gather<<<KSEL, 128, 0, stream>>>(cls, cent, bbox, maxs, labels, sidx, validArr, scal, out);
  k8_mask<<<dim3(32, 32), 64, 0, stream>>>(out, scal, mask);
  k9_nms<<<1, 64, 0, stream>>>(mask, validArr, out + KSEL * 4 + KSEL * NC + KSEL * 2);
}

// Round 3
// 373.452 us; speedup vs baseline: 1.8110x; 1.7965x over previous
//
#include <hip/hip_runtime.h>
#include <stdint.h>

#define NA 250000
#define NC 80
#define KSEL 2048
#define CONF_THF 0.05f
#define IOU_THF 0.5f
#define HBINS 1024
#define HREP 16
#define HBASE 0x3D00u

typedef unsigned int u32;
typedef unsigned long long u64;

// ---- workspace layout (bytes) ----
#define WS_HIST    0u          // 16 replicas x 1024 u32 (64KB)
#define WS_SCAL    65536u      // 16 u32: 1=above 2=kthKey 3=candCnt 4=maxCoordBits
#define WS_MAXS    65600u      // 250000 f32
#define WS_LABELS  1065600u    // 250000 i32
#define WS_CAND    2065600u    // 4096 u32
#define WS_SIDX    2081984u    // 2048 u32
#define WS_VALID   2090176u    // 2048 u32
#define WS_MASK    2098368u    // 2048*32 u64 (512KB), 8B aligned

// Correctly-rounded f32 sigmoid via double exp — ONLY for order-critical
// values (max_scores). Bit-identical to rounds 1-2 (proven to match numpy
// ranking on this input).
__device__ __forceinline__ float sigmoidf_(float x) {
  if (x >= 0.0f) {
    float ef = (float)exp(-(double)x);
    return 1.0f / (1.0f + ef);
  } else {
    float ef = (float)exp((double)x);
    return ef / (1.0f + ef);
  }
}

// Fast f32 sigmoid for value-only outputs (scores matrix; tolerance ~0.02).
__device__ __forceinline__ float sigmoid_fast(float x) {
  return 1.0f / (1.0f + __expf(-x));
}

__device__ __forceinline__ u64 bcast64(u64 v, int src) {
  u32 lo = (u32)v, hi = (u32)(v >> 32);
  lo = __shfl((int)lo, src);
  hi = __shfl((int)hi, src);
  return ((u64)hi << 32) | (u64)lo;
}

// K1: block stages 64 anchors (20KB logits + 64 centerness) to LDS with
// perfectly coalesced float4 loads; 4 lanes/anchor compute logit-max, then
// exact double-exp sigmoid products only within 2e-4 of max logit.
// Histogram: 1024 bins over high16-0x3D00, 16 replicas to kill same-line
// atomic serialization.
__global__ void __launch_bounds__(256, 4)
k1_scores(const float* __restrict__ cls, const float* __restrict__ cent,
          float* __restrict__ maxs, int* __restrict__ labels,
          u32* __restrict__ hist) {
  __shared__ float4 lds4[1280];     // 64 anchors x 80 logits
  __shared__ float lds_cent[64];
  int tid = threadIdx.x;
  int blk = blockIdx.x;
  const float4* cls4 = (const float4*)cls;
  size_t base = (size_t)blk * 1280;
#pragma unroll
  for (int k = 0; k < 5; k++) {
    int fb = tid + k * 256;
    size_t g = base + (size_t)fb;
    float4 v;
    if (g < (size_t)NA * 20) v = cls4[g];
    else { v.x = v.y = v.z = v.w = -1e30f; }
    lds4[fb] = v;
  }
  if (tid < 64) {
    int ag = blk * 64 + tid;
    lds_cent[tid] = (ag < NA) ? cent[ag] : 0.0f;
  }
  __syncthreads();
  int a = tid >> 2, p = tid & 3;
  int ag = blk * 64 + a;
  if (ag >= NA) return;
  // pass 1: max logit over the lane's 20 classes, reduce over quad
  float lm = -1e30f;
#pragma unroll
  for (int j = 0; j < 5; j++) {
    float4 v = lds4[a * 20 + p * 5 + j];
    lm = fmaxf(lm, fmaxf(fmaxf(v.x, v.y), fmaxf(v.z, v.w)));
  }
  lm = fmaxf(lm, __shfl_xor(lm, 1));
  lm = fmaxf(lm, __shfl_xor(lm, 2));
  // centerness sigmoid once per anchor, broadcast in quad
  float cp = 0.0f;
  if (p == 0) cp = sigmoidf_(lds_cent[a]);
  cp = __shfl(cp, (threadIdx.x & 63) & ~3);
  // pass 2: exact products for classes within 2e-4 of max logit
  float thresh = lm - 2e-4f;
  float bs = -1.0f; int bc = 0x7fffffff;
#pragma unroll
  for (int j = 0; j < 5; j++) {
    float4 v = lds4[a * 20 + p * 5 + j];
    float vv[4] = {v.x, v.y, v.z, v.w};
#pragma unroll
    for (int q = 0; q < 4; q++) {
      if (vv[q] >= thresh) {
        float s = sigmoidf_(vv[q]) * cp;
        int c = p * 20 + j * 4 + q;
        if (s > bs || (s == bs && c < bc)) { bs = s; bc = c; }
      }
    }
  }
#pragma unroll
  for (int off = 1; off <= 2; off <<= 1) {
    float os = __shfl_xor(bs, off);
    int   oc = __shfl_xor(bc, off);
    if (os > bs || (os == bs && oc < bc)) { bs = os; bc = oc; }
  }
  if (p == 0) {
    maxs[ag] = bs;
    labels[ag] = bc;
    u32 key = (bs > CONF_THF) ? __float_as_uint(bs) : 0u;
    if (key != 0u) {
      u32 bin = (key >> 16) - HBASE;            // in [0x4C, 0x280]
      atomicAdd(&hist[((u32)(blk & (HREP - 1)) << 10) + bin], 1u);
    }
  }
}

// K2: sum 16 replicas, 1024-thread suffix scan from top bin; pick bin B
// where suffix crosses KSEL. kth key = B<<16 (bin-granular; k6 sorts ties).
__global__ void __launch_bounds__(1024) k2_findbin(const u32* __restrict__ hist,
                                                   u32* __restrict__ scal) {
  __shared__ u32 sc[1024];
  int tid = threadIdx.x;
  int bin = 1023 - tid;            // reversed so scan = suffix sum from top
  u32 c = 0;
#pragma unroll
  for (int r = 0; r < HREP; r++) c += hist[r * HBINS + bin];
  sc[tid] = c;
  for (int off = 1; off < 1024; off <<= 1) {
    __syncthreads();
    u32 t = (tid >= off) ? sc[tid - off] : 0u;
    __syncthreads();
    sc[tid] += t;
  }
  __syncthreads();
  u32 incl = sc[tid], excl = incl - c;
  if (incl >= KSEL && excl < KSEL) {
    scal[2] = ((u32)bin + HBASE) << 16;
    scal[1] = excl;
  }
  if (tid == 1023 && incl < KSEL) {   // fewer than K candidates total
    scal[2] = 0u;
    scal[1] = incl;
  }
}

// K5: compact candidates with key >= kth (bin-granular).
__global__ void k5_compact(const float* __restrict__ maxs, u32* __restrict__ scal,
                           u32* __restrict__ cand) {
  int a = blockIdx.x * blockDim.x + threadIdx.x;
  if (a >= NA) return;
  float s = maxs[a];
  u32 key = (s > CONF_THF) ? __float_as_uint(s) : 0u;
  u32 kth = scal[2];
  // kth==0 fallback: only zero-keys with idx<KSEL are needed (smallest indices win ties)
  if (key >= kth && (key > 0u || a < KSEL)) {
    u32 pos = atomicAdd(&scal[3], 1u);
    if (pos < 4096u) cand[pos] = (u32)a;
  }
}

// K6: bitonic sort 4096 candidates by (score_bits desc, idx asc); emit top 2048.
__global__ void __launch_bounds__(1024) k6_sort(const float* __restrict__ maxs,
                                                const u32* __restrict__ cand,
                                                const u32* __restrict__ scal,
                                                u32* __restrict__ sidx,
                                                u32* __restrict__ validArr) {
  __shared__ u64 skey[4096];
  int tid = threadIdx.x;
  u32 cnt = scal[3];
  u32 n = cnt < 4096u ? cnt : 4096u;
  for (int i = tid; i < 4096; i += 1024) {
    u64 key = 0;
    if ((u32)i < n) {
      u32 a = cand[i];
      float s = maxs[a];
      u32 kb = (s > CONF_THF) ? __float_as_uint(s) : 0u;
      key = ((u64)kb << 32) | (u64)(0xFFFFFFFFu - a);
    }
    skey[i] = key;
  }
  for (int k = 2; k <= 4096; k <<= 1) {
    for (int j = k >> 1; j > 0; j >>= 1) {
      __syncthreads();
      for (int i = tid; i < 4096; i += 1024) {
        int l = i ^ j;
        if (l > i) {
          u64 A = skey[i], B = skey[l];
          bool desc = ((i & k) == 0);
          if (desc ? (A < B) : (A > B)) { skey[i] = B; skey[l] = A; }
        }
      }
    }
  }
  __syncthreads();
  for (int r = tid; r < KSEL; r += 1024) {
    u64 kk = skey[r];
    u32 a = 0xFFFFFFFFu - (u32)(kk & 0xFFFFFFFFu);
    sidx[r] = a;
    validArr[r] = ((kk >> 32) != 0ull) ? 1u : 0u;
  }
}

// K7: gather outputs + max_coord reduction. Scores output uses fast sigmoid
// (value-only, tolerance ~0.02); ordering-critical values come from maxs.
__global__ void k7_gather(const float* __restrict__ cls, const float* __restrict__ cent,
                          const float* __restrict__ bbox, const float* __restrict__ maxs,
                          const int* __restrict__ labels, const u32* __restrict__ sidx,
                          const u32* __restrict__ validArr, u32* __restrict__ scal,
                          float* __restrict__ out) {
  int r = blockIdx.x;
  int tid = threadIdx.x;
  u32 a = sidx[r];
  float* out_boxes  = out;
  float* out_scores = out + KSEL * 4;
  float* out_ms     = out + KSEL * 4 + KSEL * NC;
  float* out_lab    = out_ms + KSEL;
  if (tid < NC) {
    float cp = sigmoid_fast(cent[a]);
    float s = sigmoid_fast(cls[(size_t)a * NC + tid]) * cp;
    out_scores[(size_t)r * NC + tid] = s;
  } else if (tid < NC + 4) {
    int q = tid - NC;
    float v = bbox[(size_t)a * 4 + q];
    out_boxes[r * 4 + q] = v;
    if (validArr[r]) atomicMax((int*)&scal[4], __float_as_int(v));  // coords >= 0
  } else if (tid == NC + 4) {
    out_ms[r] = maxs[a];
  } else if (tid == NC + 5) {
    out_lab[r] = (float)labels[a];
  }
}

// K8: 64x64 IoU tiles -> suppression bitmask.
__global__ void k8_mask(const float* __restrict__ out, const u32* __restrict__ scal,
                        u64* __restrict__ mask) {
  __shared__ float cx1[64], cy1[64], cx2[64], cy2[64], car[64];
  const float* boxes = out;
  const float* lab = out + KSEL * 4 + KSEL * NC + KSEL;
  float mc1 = __int_as_float(*(const int*)&scal[4]) + 1.0f;
  int t = threadIdx.x;
  int j = blockIdx.x * 64 + t;
  {
    float off = lab[j] * mc1;
    float x1 = boxes[j * 4 + 0] + off, y1 = boxes[j * 4 + 1] + off;
    float x2 = boxes[j * 4 + 2] + off, y2 = boxes[j * 4 + 3] + off;
    cx1[t] = x1; cy1[t] = y1; cx2[t] = x2; cy2[t] = y2;
    car[t] = (x2 - x1) * (y2 - y1);
  }
  __syncthreads();
  int i = blockIdx.y * 64 + t;
  float off = lab[i] * mc1;
  float x1 = boxes[i * 4 + 0] + off, y1 = boxes[i * 4 + 1] + off;
  float x2 = boxes[i * 4 + 2] + off, y2 = boxes[i * 4 + 3] + off;
  float ar = (x2 - x1) * (y2 - y1);
  u64 bits = 0;
  for (int jj = 0; jj < 64; jj++) {
    float ix = fminf(x2, cx2[jj]) - fmaxf(x1, cx1[jj]);
    float iy = fminf(y2, cy2[jj]) - fmaxf(y1, cy1[jj]);
    float inter = fmaxf(ix, 0.0f) * fmaxf(iy, 0.0f);
    float uni = ar + car[jj] - inter;
    float iou = inter / fmaxf(uni, 1e-9f);
    if (iou > IOU_THF) bits |= (1ull << jj);
  }
  mask[(size_t)i * 32 + blockIdx.x] = bits;
}

// K9: single-wave sequential greedy NMS with 16-row register prefetch.
__global__ void k9_nms(const u64* __restrict__ mask, const u32* __restrict__ validArr,
                       float* __restrict__ out_keep) {
  int lane = threadIdx.x;
  u64 vw = 0, remv = 0;
  if (lane < 32) {
    const u32* va = validArr + lane * 64;
#pragma unroll 8
    for (int b = 0; b < 64; b++) vw |= ((u64)(va[b] & 1u)) << b;
  }
  u64 cur[16], nxt[16];
  if (lane < 32) {
#pragma unroll
    for (int k = 0; k < 16; k++) cur[k] = mask[(size_t)k * 32 + lane];
  }
  for (int g = 0; g < KSEL; g += 16) {
    if (g + 16 < KSEL && lane < 32) {
#pragma unroll
      for (int k = 0; k < 16; k++) nxt[k] = mask[(size_t)(g + 16 + k) * 32 + lane];
    }
#pragma unroll
    for (int k = 0; k < 16; k++) {
      int i = g + k;
      int wi = i >> 6, bi = i & 63;
      u64 rw = bcast64(remv, wi);
      u64 vv = bcast64(vw, wi);
      bool alive = (((vv >> bi) & 1ull) != 0ull) && (((rw >> bi) & 1ull) == 0ull);
      remv |= alive ? cur[k] : 0ull;
      if (lane == 0) out_keep[i] = alive ? 1.0f : 0.0f;
    }
#pragma unroll
    for (int k = 0; k < 16; k++) cur[k] = nxt[k];
  }
}

extern "C" void kernel_launch(void* const* d_in, const int* in_sizes, int n_in,
                              void* d_out, int out_size, void* d_ws, size_t ws_size,
                              hipStream_t stream) {
  const float* cls  = (const float*)d_in[0];
  const float* bbox = (const float*)d_in[1];
  const float* cent = (const float*)d_in[2];
  float* out = (float*)d_out;
  char* ws = (char*)d_ws;
  u32* hist     = (u32*)(ws + WS_HIST);
  u32* scal     = (u32*)(ws + WS_SCAL);
  float* maxs   = (float*)(ws + WS_MAXS);
  int* labels   = (int*)(ws + WS_LABELS);
  u32* cand     = (u32*)(ws + WS_CAND);
  u32* sidx     = (u32*)(ws + WS_SIDX);
  u32* validArr = (u32*)(ws + WS_VALID);
  u64* mask     = (u64*)(ws + WS_MASK);

  (void)in_sizes; (void)n_in; (void)out_size; (void)ws_size;

  // zero hist replicas + scalars each call (deterministic across replays)
  hipMemsetAsync(ws, 0, WS_MAXS, stream);

  k1_scores<<<(NA + 63) / 64, 256, 0, stream>>>(cls, cent, maxs, labels, hist);
  k2_findbin<<<1, 1024, 0, stream>>>(hist, scal);
  k5_compact<<<(NA + 255) / 256, 256, 0, stream>>>(maxs, scal, cand);
  k6_sort<<<1, 1024, 0, stream>>>(maxs, cand, scal, sidx, validArr);
  k7_gather<<<KSEL, 128, 0, stream>>>(cls, cent, bbox, maxs, labels, sidx, validArr, scal, out);
  k8_mask<<<dim3(32, 32), 64, 0, stream>>>(out, scal, mask);
  k9_nms<<<1, 64, 0, stream>>>(mask, validArr, out + KSEL * 4 + KSEL * NC + KSEL * 2);
}

// Round 4
// 279.163 us; speedup vs baseline: 2.4227x; 1.3378x over previous
//
#include <hip/hip_runtime.h>
#include <stdint.h>

#define NA 250000
#define NC 80
#define KSEL 2048
#define CONF_THF 0.05f
#define IOU_THF 0.5f
#define HBINS 1024
#define HREP 16
#define HBASE 0x3D00u

typedef unsigned int u32;
typedef unsigned long long u64;

// ---- workspace layout (bytes) ----
#define WS_HIST    0u          // 16 replicas x 1024 u32 (64KB)
#define WS_SCAL    65536u      // 16 u32: 1=above 2=kthKey 3=candCnt 4=maxCoordBits
#define WS_MAXS    65600u      // 250000 f32
#define WS_LABELS  1065600u    // 250000 i32
#define WS_CAND    2065600u    // 4096 u32
#define WS_SIDX    2081984u    // 2048 u32
#define WS_VALID   2090176u    // 2048 u32
#define WS_MASK    2098368u    // 2048*32 u64 (512KB), 8B aligned
#define WS_DIAGT   2622656u    // 2048 u64 (16KB) transposed diagonal blocks
#define WS_VBITS   2639040u    // 32 u64 valid bitmask per chunk

// Correctly-rounded f32 sigmoid via double exp — ONLY for order-critical
// values (max_scores). Bit-identical to rounds 1-3 (proven to match numpy
// ranking on this input).
__device__ __forceinline__ float sigmoidf_(float x) {
  if (x >= 0.0f) {
    float ef = (float)exp(-(double)x);
    return 1.0f / (1.0f + ef);
  } else {
    float ef = (float)exp((double)x);
    return ef / (1.0f + ef);
  }
}

// Fast f32 sigmoid for value-only outputs (scores matrix; tolerance ~0.02).
__device__ __forceinline__ float sigmoid_fast(float x) {
  return 1.0f / (1.0f + __expf(-x));
}

__device__ __forceinline__ u64 shfl64(u64 v, int src) {
  u32 lo = (u32)v, hi = (u32)(v >> 32);
  lo = __shfl((int)lo, src);
  hi = __shfl((int)hi, src);
  return ((u64)hi << 32) | (u64)lo;
}

__device__ __forceinline__ u64 rfl64(u64 v) {
  u32 lo = __builtin_amdgcn_readfirstlane((u32)v);
  u32 hi = __builtin_amdgcn_readfirstlane((u32)(v >> 32));
  return ((u64)hi << 32) | (u64)lo;
}

// K1: block stages 64 anchors (20KB logits + 64 centerness) to LDS with
// perfectly coalesced float4 loads; 4 lanes/anchor compute logit-max, then
// exact double-exp sigmoid products only within 2e-4 of max logit.
// Histogram: 1024 bins over high16-0x3D00, 16 replicas.
__global__ void __launch_bounds__(256, 4)
k1_scores(const float* __restrict__ cls, const float* __restrict__ cent,
          float* __restrict__ maxs, int* __restrict__ labels,
          u32* __restrict__ hist) {
  __shared__ float4 lds4[1280];     // 64 anchors x 80 logits
  __shared__ float lds_cent[64];
  int tid = threadIdx.x;
  int blk = blockIdx.x;
  const float4* cls4 = (const float4*)cls;
  size_t base = (size_t)blk * 1280;
#pragma unroll
  for (int k = 0; k < 5; k++) {
    int fb = tid + k * 256;
    size_t g = base + (size_t)fb;
    float4 v;
    if (g < (size_t)NA * 20) v = cls4[g];
    else { v.x = v.y = v.z = v.w = -1e30f; }
    lds4[fb] = v;
  }
  if (tid < 64) {
    int ag = blk * 64 + tid;
    lds_cent[tid] = (ag < NA) ? cent[ag] : 0.0f;
  }
  __syncthreads();
  int a = tid >> 2, p = tid & 3;
  int ag = blk * 64 + a;
  if (ag >= NA) return;
  float lm = -1e30f;
#pragma unroll
  for (int j = 0; j < 5; j++) {
    float4 v = lds4[a * 20 + p * 5 + j];
    lm = fmaxf(lm, fmaxf(fmaxf(v.x, v.y), fmaxf(v.z, v.w)));
  }
  lm = fmaxf(lm, __shfl_xor(lm, 1));
  lm = fmaxf(lm, __shfl_xor(lm, 2));
  float cp = 0.0f;
  if (p == 0) cp = sigmoidf_(lds_cent[a]);
  cp = __shfl(cp, (threadIdx.x & 63) & ~3);
  float thresh = lm - 2e-4f;
  float bs = -1.0f; int bc = 0x7fffffff;
#pragma unroll
  for (int j = 0; j < 5; j++) {
    float4 v = lds4[a * 20 + p * 5 + j];
    float vv[4] = {v.x, v.y, v.z, v.w};
#pragma unroll
    for (int q = 0; q < 4; q++) {
      if (vv[q] >= thresh) {
        float s = sigmoidf_(vv[q]) * cp;
        int c = p * 20 + j * 4 + q;
        if (s > bs || (s == bs && c < bc)) { bs = s; bc = c; }
      }
    }
  }
#pragma unroll
  for (int off = 1; off <= 2; off <<= 1) {
    float os = __shfl_xor(bs, off);
    int   oc = __shfl_xor(bc, off);
    if (os > bs || (os == bs && oc < bc)) { bs = os; bc = oc; }
  }
  if (p == 0) {
    maxs[ag] = bs;
    labels[ag] = bc;
    u32 key = (bs > CONF_THF) ? __float_as_uint(bs) : 0u;
    if (key != 0u) {
      u32 bin = (key >> 16) - HBASE;
      atomicAdd(&hist[((u32)(blk & (HREP - 1)) << 10) + bin], 1u);
    }
  }
}

// K2: sum 16 replicas, 1024-thread suffix scan from top bin.
__global__ void __launch_bounds__(1024) k2_findbin(const u32* __restrict__ hist,
                                                   u32* __restrict__ scal) {
  __shared__ u32 sc[1024];
  int tid = threadIdx.x;
  int bin = 1023 - tid;
  u32 c = 0;
#pragma unroll
  for (int r = 0; r < HREP; r++) c += hist[r * HBINS + bin];
  sc[tid] = c;
  for (int off = 1; off < 1024; off <<= 1) {
    __syncthreads();
    u32 t = (tid >= off) ? sc[tid - off] : 0u;
    __syncthreads();
    sc[tid] += t;
  }
  __syncthreads();
  u32 incl = sc[tid], excl = incl - c;
  if (incl >= KSEL && excl < KSEL) {
    scal[2] = ((u32)bin + HBASE) << 16;
    scal[1] = excl;
  }
  if (tid == 1023 && incl < KSEL) {
    scal[2] = 0u;
    scal[1] = incl;
  }
}

// K5: compact candidates with key >= kth (bin-granular).
__global__ void k5_compact(const float* __restrict__ maxs, u32* __restrict__ scal,
                           u32* __restrict__ cand) {
  int a = blockIdx.x * blockDim.x + threadIdx.x;
  if (a >= NA) return;
  float s = maxs[a];
  u32 key = (s > CONF_THF) ? __float_as_uint(s) : 0u;
  u32 kth = scal[2];
  if (key >= kth && (key > 0u || a < KSEL)) {
    u32 pos = atomicAdd(&scal[3], 1u);
    if (pos < 4096u) cand[pos] = (u32)a;
  }
}

// K6: bitonic sort 4096 candidates by (score desc, idx asc); emit top 2048
// + per-chunk valid bitmasks.
__global__ void __launch_bounds__(1024) k6_sort(const float* __restrict__ maxs,
                                                const u32* __restrict__ cand,
                                                const u32* __restrict__ scal,
                                                u32* __restrict__ sidx,
                                                u32* __restrict__ validArr,
                                                u64* __restrict__ validBits) {
  __shared__ u64 skey[4096];
  int tid = threadIdx.x;
  u32 cnt = scal[3];
  u32 n = cnt < 4096u ? cnt : 4096u;
  for (int i = tid; i < 4096; i += 1024) {
    u64 key = 0;
    if ((u32)i < n) {
      u32 a = cand[i];
      float s = maxs[a];
      u32 kb = (s > CONF_THF) ? __float_as_uint(s) : 0u;
      key = ((u64)kb << 32) | (u64)(0xFFFFFFFFu - a);
    }
    skey[i] = key;
  }
  for (int k = 2; k <= 4096; k <<= 1) {
    for (int j = k >> 1; j > 0; j >>= 1) {
      __syncthreads();
      for (int i = tid; i < 4096; i += 1024) {
        int l = i ^ j;
        if (l > i) {
          u64 A = skey[i], B = skey[l];
          bool desc = ((i & k) == 0);
          if (desc ? (A < B) : (A > B)) { skey[i] = B; skey[l] = A; }
        }
      }
    }
  }
  __syncthreads();
  for (int r = tid; r < KSEL; r += 1024) {
    u64 kk = skey[r];
    u32 a = 0xFFFFFFFFu - (u32)(kk & 0xFFFFFFFFu);
    bool valid = (kk >> 32) != 0ull;
    sidx[r] = a;
    validArr[r] = valid ? 1u : 0u;
    u64 vb = __ballot(valid);       // wave-consecutive r -> chunk bits
    if ((tid & 63) == 0) validBits[r >> 6] = vb;
  }
}

// K7: gather outputs + max_coord reduction.
__global__ void k7_gather(const float* __restrict__ cls, const float* __restrict__ cent,
                          const float* __restrict__ bbox, const float* __restrict__ maxs,
                          const int* __restrict__ labels, const u32* __restrict__ sidx,
                          const u32* __restrict__ validArr, u32* __restrict__ scal,
                          float* __restrict__ out) {
  int r = blockIdx.x;
  int tid = threadIdx.x;
  u32 a = sidx[r];
  float* out_boxes  = out;
  float* out_scores = out + KSEL * 4;
  float* out_ms     = out + KSEL * 4 + KSEL * NC;
  float* out_lab    = out_ms + KSEL;
  if (tid < NC) {
    float cp = sigmoid_fast(cent[a]);
    float s = sigmoid_fast(cls[(size_t)a * NC + tid]) * cp;
    out_scores[(size_t)r * NC + tid] = s;
  } else if (tid < NC + 4) {
    int q = tid - NC;
    float v = bbox[(size_t)a * 4 + q];
    out_boxes[r * 4 + q] = v;
    if (validArr[r]) atomicMax((int*)&scal[4], __float_as_int(v));
  } else if (tid == NC + 4) {
    out_ms[r] = maxs[a];
  } else if (tid == NC + 5) {
    out_lab[r] = (float)labels[a];
  }
}

// K8: 64x64 IoU tiles -> row bitmask; diagonal blocks also emit the
// ballot-transposed columns for k9's serial phase.
__global__ void k8_mask(const float* __restrict__ out, const u32* __restrict__ scal,
                        u64* __restrict__ mask, u64* __restrict__ diagT) {
  __shared__ float cx1[64], cy1[64], cx2[64], cy2[64], car[64];
  const float* boxes = out;
  const float* lab = out + KSEL * 4 + KSEL * NC + KSEL;
  float mc1 = __int_as_float(*(const int*)&scal[4]) + 1.0f;
  int t = threadIdx.x;
  int j = blockIdx.x * 64 + t;
  {
    float off = lab[j] * mc1;
    float x1 = boxes[j * 4 + 0] + off, y1 = boxes[j * 4 + 1] + off;
    float x2 = boxes[j * 4 + 2] + off, y2 = boxes[j * 4 + 3] + off;
    cx1[t] = x1; cy1[t] = y1; cx2[t] = x2; cy2[t] = y2;
    car[t] = (x2 - x1) * (y2 - y1);
  }
  __syncthreads();
  int i = blockIdx.y * 64 + t;
  float off = lab[i] * mc1;
  float x1 = boxes[i * 4 + 0] + off, y1 = boxes[i * 4 + 1] + off;
  float x2 = boxes[i * 4 + 2] + off, y2 = boxes[i * 4 + 3] + off;
  float ar = (x2 - x1) * (y2 - y1);
  u64 bits = 0;
  for (int jj = 0; jj < 64; jj++) {
    float ix = fminf(x2, cx2[jj]) - fmaxf(x1, cx1[jj]);
    float iy = fminf(y2, cy2[jj]) - fmaxf(y1, cy1[jj]);
    float inter = fmaxf(ix, 0.0f) * fmaxf(iy, 0.0f);
    float uni = ar + car[jj] - inter;
    float iou = inter / fmaxf(uni, 1e-9f);
    if (iou > IOU_THF) bits |= (1ull << jj);
  }
  mask[(size_t)i * 32 + blockIdx.x] = bits;
  if (blockIdx.x == blockIdx.y) {
    u64 colv = 0;
    for (int jj = 0; jj < 64; jj++) {
      u64 b = __ballot(((bits >> jj) & 1ull) != 0ull);
      if (t == jj) colv = b;
    }
    diagT[blockIdx.x * 64 + t] = colv;
  }
}

// K9: single-wave greedy NMS, broadcast-free serial chain.
// Lane j holds column j of the current chunk's transposed diagonal block;
// per kept box: ctz -> bit-extract -> ballot -> scalar AND-NOT (~30cy).
// Cross-chunk suppression rows prefetched during the serial phase.
__global__ void k9_nms(const u64* __restrict__ mask, const u64* __restrict__ diagT,
                       const u64* __restrict__ validBits,
                       float* __restrict__ out_keep) {
  int lane = threadIdx.x;      // 64 lanes, one wave
  int l5 = lane & 31;          // target chunk for cross-suppression rows
  int h = lane >> 5;           // row-half handled by this lane
  u64 remv = 0;                // suppression accumulated for chunk l5 (half h)
  u64 colbits = diagT[lane];   // chunk 0 transposed diagonal
  u64 vchunk = (lane < 32) ? validBits[lane] : 0ull;

  for (int c = 0; c < 32; c++) {
    // current chunk's incoming suppression + valid bits (uniform scalars)
    u64 rc = rfl64(shfl64(remv, c) | shfl64(remv, c + 32));
    u64 vb = rfl64(shfl64(vchunk, c));

    // prefetch this chunk's cross-suppression rows (independent of decisions)
    u64 rows[32];
#pragma unroll
    for (int k = 0; k < 32; k++)
      rows[k] = mask[(size_t)(c * 64 + h * 32 + k) * 32 + l5];
    u64 colnext = (c < 31) ? diagT[(c + 1) * 64 + lane] : 0ull;

    // serial greedy within chunk (uniform across lanes, ~30cy per KEPT box)
    u64 rem = vb & ~rc;
    u64 keep = 0;
    while (rem) {
      int i = __ffsll((long long)rem) - 1;
      u64 bit = 1ull << i;
      keep |= bit;
      u64 row = __ballot(((colbits >> i) & 1ull) != 0ull);
      u64 hm = (i < 63) ? (~0ull << (i + 1)) : 0ull;
      rem &= ~((row & hm) | bit);
    }
    out_keep[c * 64 + lane] = ((keep >> lane) & 1ull) ? 1.0f : 0.0f;

    // epilogue: OR kept rows into future-chunk accumulators
    u32 khalf = h ? (u32)(keep >> 32) : (u32)keep;
#pragma unroll
    for (int k = 0; k < 32; k++) {
      u64 m = 0ull - (u64)((khalf >> k) & 1u);
      remv |= rows[k] & m;
    }
    colbits = colnext;
  }
}

extern "C" void kernel_launch(void* const* d_in, const int* in_sizes, int n_in,
                              void* d_out, int out_size, void* d_ws, size_t ws_size,
                              hipStream_t stream) {
  const float* cls  = (const float*)d_in[0];
  const float* bbox = (const float*)d_in[1];
  const float* cent = (const float*)d_in[2];
  float* out = (float*)d_out;
  char* ws = (char*)d_ws;
  u32* hist      = (u32*)(ws + WS_HIST);
  u32* scal      = (u32*)(ws + WS_SCAL);
  float* maxs    = (float*)(ws + WS_MAXS);
  int* labels    = (int*)(ws + WS_LABELS);
  u32* cand      = (u32*)(ws + WS_CAND);
  u32* sidx      = (u32*)(ws + WS_SIDX);
  u32* validArr  = (u32*)(ws + WS_VALID);
  u64* mask      = (u64*)(ws + WS_MASK);
  u64* diagT     = (u64*)(ws + WS_DIAGT);
  u64* validBits = (u64*)(ws + WS_VBITS);

  (void)in_sizes; (void)n_in; (void)out_size; (void)ws_size;

  hipMemsetAsync(ws, 0, WS_MAXS, stream);

  k1_scores<<<(NA + 63) / 64, 256, 0, stream>>>(cls, cent, maxs, labels, hist);
  k2_findbin<<<1, 1024, 0, stream>>>(hist, scal);
  k5_compact<<<(NA + 255) / 256, 256, 0, stream>>>(maxs, scal, cand);
  k6_sort<<<1, 1024, 0, stream>>>(maxs, cand, scal, sidx, validArr, validBits);
  k7_gather<<<KSEL, 128, 0, stream>>>(cls, cent, bbox, maxs, labels, sidx, validArr, scal, out);
  k8_mask<<<dim3(32, 32), 64, 0, stream>>>(out, scal, mask, diagT);
  k9_nms<<<1, 64, 0, stream>>>(mask, diagT, validBits, out + KSEL * 4 + KSEL * NC + KSEL * 2);
}